// Round 8
// baseline (290.763 us; speedup 1.0000x reference)
//
#include <hip/hip_runtime.h>

#define N_NODES 100000
#define NF      128
#define NE      600000
#define NG      1000
#define EPSF    1e-5f

#define STATS_NB (N_NODES / 32)              // 3125 blocks, 4 waves x 8 rows
#define DEG_NB   (((NE / 4) + 255) / 256)    // 586 blocks, int4 edges
#define ALLOC_NB ((N_NODES + 255) / 256)     // 391
#define BRED_NB  64

typedef float v2f __attribute__((ext_vector_type(2)));

// ================= K1: per-graph stats ∥ degree count =================
__global__ __launch_bounds__(256) void k1_stats_deg(
    const float* __restrict__ x, const int* __restrict__ gid,
    const int* __restrict__ edst,
    float* __restrict__ gsum, float* __restrict__ gsq, int* __restrict__ cnt,
    int* __restrict__ deg)
{
    if (blockIdx.x >= STATS_NB) {
        int t = (blockIdx.x - STATS_NB) * 256 + threadIdx.x;
        if (t < NE / 4) {
            const int4 d4 = reinterpret_cast<const int4*>(edst)[t];
            atomicAdd(&deg[d4.x], 1);
            atomicAdd(&deg[d4.y], 1);
            atomicAdd(&deg[d4.z], 1);
            atomicAdd(&deg[d4.w], 1);
        }
        return;
    }
    // wave owns 8 contiguous rows; graph_id sorted -> run-flush
    const int wave = threadIdx.x >> 6;
    const int lane = threadIdx.x & 63;
    const int f = lane * 2;
    const int r0 = blockIdx.x * 32 + wave * 8;
    const int r1 = r0 + 8;

    float gsx = 0.f, gsy = 0.f, gqx = 0.f, gqy = 0.f;
    int cur = gid[r0];
    int runStart = r0;

    for (int r = r0; r < r1; ++r) {
        int g = gid[r];                  // wave-uniform
        if (g != cur) {
            atomicAdd(&gsum[cur * NF + f],     gsx);
            atomicAdd(&gsum[cur * NF + f + 1], gsy);
            atomicAdd(&gsq [cur * NF + f],     gqx);
            atomicAdd(&gsq [cur * NF + f + 1], gqy);
            if (lane == 0) atomicAdd(&cnt[cur], r - runStart);
            gsx = gsy = gqx = gqy = 0.f;
            cur = g; runStart = r;
        }
        const float2 v = *reinterpret_cast<const float2*>(x + (size_t)r * NF + f);
        gsx += v.x; gsy += v.y; gqx += v.x * v.x; gqy += v.y * v.y;
    }
    atomicAdd(&gsum[cur * NF + f],     gsx);
    atomicAdd(&gsum[cur * NF + f + 1], gsy);
    atomicAdd(&gsq [cur * NF + f],     gqx);
    atomicAdd(&gsq [cur * NF + f + 1], gqy);
    if (lane == 0) atomicAdd(&cnt[cur], r1 - runStart);
}

// ================= K2: segment alloc (scan-free) ∥ batch reduction =================
__global__ __launch_bounds__(256) void k2_alloc_bred(
    const int* __restrict__ deg, int2* __restrict__ odeg, int* __restrict__ cursor,
    int* __restrict__ total,
    const float* __restrict__ gsum, const float* __restrict__ gsq,
    float* __restrict__ bsum, float* __restrict__ bsq)
{
    if (blockIdx.x < ALLOC_NB) {
        const int i = blockIdx.x * 256 + threadIdx.x;
        const int lane = threadIdx.x & 63;
        int d = (i < N_NODES) ? deg[i] : 0;
        int p = d;                           // inclusive wave prefix sum
#pragma unroll
        for (int st = 1; st < 64; st <<= 1) {
            int v = __shfl_up(p, st, 64);
            if (lane >= st) p += v;
        }
        int wtot = __shfl(p, 63, 64);
        int base = 0;
        if (lane == 63) base = atomicAdd(total, wtot);
        base = __shfl(base, 63, 64);
        if (i < N_NODES) {
            int o = base + p - d;            // exclusive start of my segment
            odeg[i] = make_int2(o, d);
            cursor[i] = o;
        }
    } else {
        // bsum[f] = sum_g gsum[g][f]
        int b = blockIdx.x - ALLOC_NB;
        int t = threadIdx.x;
        int f = t & 127, gl = t >> 7;
        float s = 0.f, q = 0.f;
#pragma unroll
        for (int k = 0; k < 8; ++k) {
            int g = b * 16 + gl * 8 + k;
            if (g < NG) { s += gsum[g * NF + f]; q += gsq[g * NF + f]; }
        }
        atomicAdd(&bsum[f], s);
        atomicAdd(&bsq[f], q);
    }
}

// ================= K3: CSR fill only =================
__global__ __launch_bounds__(256) void k3_fill(
    const int* __restrict__ esrc, const int* __restrict__ edst,
    int* __restrict__ cursor, int* __restrict__ nbr)
{
    int t = blockIdx.x * 256 + threadIdx.x;
    if (t < NE / 4) {
        const int4 d4 = reinterpret_cast<const int4*>(edst)[t];
        const int4 s4 = reinterpret_cast<const int4*>(esrc)[t];
        int p;
        p = atomicAdd(&cursor[d4.x], 1); nbr[p] = s4.x;
        p = atomicAdd(&cursor[d4.y], 1); nbr[p] = s4.y;
        p = atomicAdd(&cursor[d4.z], 1); nbr[p] = s4.z;
        p = atomicAdd(&cursor[d4.w], 1); nbr[p] = s4.w;
    }
}

// ================= K5: fused final, 1 node/wave, constants folded inline =================
__global__ __launch_bounds__(256) void k5_final(
    const float* __restrict__ x, const int* __restrict__ gid,
    const float* __restrict__ gsum, const float* __restrict__ gsq,
    const int* __restrict__ cnt,
    const float* __restrict__ bsum, const float* __restrict__ bsq,
    const float* __restrict__ gamma, const float* __restrict__ beta,
    const float* __restrict__ lb, const float* __restrict__ lg,
    const float* __restrict__ la, const float* __restrict__ ln,
    const int2* __restrict__ odeg, const int* __restrict__ nbr,
    float* __restrict__ out)
{
    const int wave = threadIdx.x >> 6;
    const int lane = threadIdx.x & 63;
    const int i = blockIdx.x * 4 + wave;
    const int f = lane * 2;
    const int f1 = f + 1;

    const float2 xi = *reinterpret_cast<const float2*>(x + (size_t)i * NF + f);

    // ---- adjacency gather first (longest-latency part): predicated 8-deep ----
    const int2 od = odeg[i];
    const int s0 = od.x, dg = od.y;
    float asx = 0.f, asy = 0.f, aqx = 0.f, aqy = 0.f;
    for (int e = 0; e < dg; e += 8) {
        int idx[8];
#pragma unroll
        for (int k = 0; k < 8; ++k)
            idx[k] = nbr[(e + k < dg) ? (s0 + e + k) : s0];
#pragma unroll
        for (int k = 0; k < 8; ++k) {
            const float2 v = *reinterpret_cast<const float2*>(x + (size_t)idx[k] * NF + f);
            const float m = (e + k < dg) ? 1.f : 0.f;
            asx += m * v.x; asy += m * v.y;
            aqx += m * v.x * v.x; aqy += m * v.y * v.y;
        }
    }

    // ---- per-feature constants, recomputed inline (broadcast loads, cheap VALU) ----
    const float invN = 1.0f / (float)N_NODES;
    float mbx = bsum[f]  * invN, mby = bsum[f1] * invN;
    float vbx = bsq[f]  * invN - mbx * mbx;             // no clamp: matches reference
    float vby = bsq[f1] * invN - mby * mby;
    float rvbx = rsqrtf(vbx + EPSF), rvby = rsqrtf(vby + EPSF);

    float l0x = lb[f],  l1x = lg[f],  l2x = la[f],  l3x = ln[f];
    float l0y = lb[f1], l1y = lg[f1], l2y = la[f1], l3y = ln[f1];
    float mx = fmaxf(fmaxf(l0x, l1x), fmaxf(l2x, l3x));
    float my = fmaxf(fmaxf(l0y, l1y), fmaxf(l2y, l3y));
    float w0x = __expf(l0x - mx), w1x = __expf(l1x - mx), w2x = __expf(l2x - mx), w3x = __expf(l3x - mx);
    float w0y = __expf(l0y - my), w1y = __expf(l1y - my), w2y = __expf(l2y - my), w3y = __expf(l3y - my);
    float rsx = gamma[f]  / (w0x + w1x + w2x + w3x);
    float rsy = gamma[f1] / (w0y + w1y + w2y + w3y);
    w0x *= rsx; w1x *= rsx; w2x *= rsx; w3x *= rsx;
    w0y *= rsy; w1y *= rsy; w2y *= rsy; w3y *= rsy;
    const float btx = beta[f], bty = beta[f1];

    // ---- batch norm ----
    float xbx = (xi.x - mbx) * rvbx;
    float xby = (xi.y - mby) * rvby;

    // ---- graph norm from raw tables ----
    const int g = gid[i];
    float c = (float)cnt[g]; if (c < 1.f) c = 1.f;
    float rc = 1.0f / c;
    const float2 gs = *reinterpret_cast<const float2*>(gsum + (size_t)g * NF + f);
    const float2 gq = *reinterpret_cast<const float2*>(gsq  + (size_t)g * NF + f);
    float mgx = gs.x * rc, mgy = gs.y * rc;
    float vgx = gq.x * rc - mgx * mgx; if (vgx < 0.f) vgx = 0.f;
    float vgy = gq.y * rc - mgy * mgy; if (vgy < 0.f) vgy = 0.f;
    float xgx = (xi.x - mgx) * rsqrtf(vgx + EPSF);
    float xgy = (xi.y - mgy) * rsqrtf(vgy + EPSF);

    // ---- node norm (wave reductions) ----
    float s = xi.x + xi.y;
#pragma unroll
    for (int d = 1; d < 64; d <<= 1) s += __shfl_xor(s, d, 64);
    const float mn = s * (1.0f / NF);
    float dxx = xi.x - mn, dyy = xi.y - mn;
    float q = dxx * dxx + dyy * dyy;
#pragma unroll
    for (int d = 1; d < 64; d <<= 1) q += __shfl_xor(q, d, 64);
    const float rvn = rsqrtf(q * (1.0f / NF) + EPSF);
    float xnx = dxx * rvn, xny = dyy * rvn;

    // ---- adjacency finish ----
    float dgc = (float)dg; if (dgc < 1.f) dgc = 1.f;
    float rdg = 1.0f / dgc;
    float max_ = asx * rdg, may_ = asy * rdg;
    float vax = aqx * rdg - max_ * max_; if (vax < 0.f) vax = 0.f;
    float vay = aqy * rdg - may_ * may_; if (vay < 0.f) vay = 0.f;
    float xax = (xi.x - max_) * rsqrtf(vax + EPSF);
    float xay = (xi.y - may_) * rsqrtf(vay + EPSF);

    // ---- combine; non-temporal store (don't pollute L2 gather working set) ----
    v2f o;
    o.x = w0x * xbx + w1x * xgx + w2x * xax + w3x * xnx + btx;
    o.y = w0y * xby + w1y * xgy + w2y * xay + w3y * xny + bty;
    __builtin_nontemporal_store(o, reinterpret_cast<v2f*>(out + (size_t)i * NF + f));
}

extern "C" void kernel_launch(void* const* d_in, const int* in_sizes, int n_in,
                              void* d_out, int out_size, void* d_ws, size_t ws_size,
                              hipStream_t stream) {
    const float* x     = (const float*)d_in[0];
    const float* gamma = (const float*)d_in[1];
    const float* beta  = (const float*)d_in[2];
    const float* lb    = (const float*)d_in[3];
    const float* lg    = (const float*)d_in[4];
    const float* la    = (const float*)d_in[5];
    const float* ln    = (const float*)d_in[6];
    const int*   gid   = (const int*)d_in[7];
    const int*   esrc  = (const int*)d_in[8];
    const int*   edst  = (const int*)d_in[9];
    float*       out   = (float*)d_out;

    // ---- workspace layout (4B units); zeroed region first ----
    float* ws    = (float*)d_ws;
    float* bsum  = ws;                              // 128
    float* bsq   = bsum + NF;                       // 128
    float* gsum  = bsq + NF;                        // NG*NF
    float* gsq   = gsum + (size_t)NG * NF;          // NG*NF
    int*   cnt   = (int*)(gsq + (size_t)NG * NF);   // NG
    int*   deg   = cnt + NG;                        // N
    int*   total = deg + N_NODES;                   // 1 (+1 pad)
    // ---- zeroed region ends here ----
    int*   cursor= total + 2;                       // N
    int2*  odeg  = (int2*)(cursor + N_NODES);       // N int2 (8B-aligned)
    int*   nbr   = (int*)(odeg + N_NODES);          // NE

    const size_t zero_elems = (size_t)2 * NF + (size_t)2 * NG * NF + NG + N_NODES + 2;
    hipMemsetAsync(d_ws, 0, zero_elems * sizeof(float), stream);

    k1_stats_deg<<<STATS_NB + DEG_NB, 256, 0, stream>>>(
        x, gid, edst, gsum, gsq, cnt, deg);
    k2_alloc_bred<<<ALLOC_NB + BRED_NB, 256, 0, stream>>>(
        deg, odeg, cursor, total, gsum, gsq, bsum, bsq);
    k3_fill<<<DEG_NB, 256, 0, stream>>>(esrc, edst, cursor, nbr);
    k5_final<<<N_NODES / 4, 256, 0, stream>>>(
        x, gid, gsum, gsq, cnt, bsum, bsq, gamma, beta, lb, lg, la, ln,
        odeg, nbr, out);
}

// Round 9
// 281.278 us; speedup vs baseline: 1.0337x; 1.0337x over previous
//
#include <hip/hip_runtime.h>

#define N_NODES 100000
#define NF      128
#define NE      600000
#define NG      1000
#define EPSF    1e-5f

#define STATS_NB (N_NODES / 32)              // 3125 blocks, 4 waves x 8 rows
#define DEG_NB   (((NE / 4) + 255) / 256)    // 586 blocks, int4 edges
#define ALLOC_NB ((N_NODES + 255) / 256)     // 391
#define BRED_NB  64
#define PREP_NB  ((NG * NF) / 256 + 1)       // 501

// ================= K1: per-graph stats (prefetched) ∥ degree count =================
__global__ __launch_bounds__(256) void k1_stats_deg(
    const float* __restrict__ x, const int* __restrict__ gid,
    const int* __restrict__ edst,
    float* __restrict__ gsum, float* __restrict__ gsq, int* __restrict__ cnt,
    int* __restrict__ deg)
{
    if (blockIdx.x >= STATS_NB) {
        int t = (blockIdx.x - STATS_NB) * 256 + threadIdx.x;
        if (t < NE / 4) {
            const int4 d4 = reinterpret_cast<const int4*>(edst)[t];
            atomicAdd(&deg[d4.x], 1);
            atomicAdd(&deg[d4.y], 1);
            atomicAdd(&deg[d4.z], 1);
            atomicAdd(&deg[d4.w], 1);
        }
        return;
    }
    // wave owns 8 contiguous rows; issue ALL loads before the run-flush logic (MLP)
    const int wave = threadIdx.x >> 6;
    const int lane = threadIdx.x & 63;
    const int f = lane * 2;
    const int r0 = blockIdx.x * 32 + wave * 8;

    float2 v[8];
    int g8[8];
#pragma unroll
    for (int k = 0; k < 8; ++k) {
        v[k] = *reinterpret_cast<const float2*>(x + (size_t)(r0 + k) * NF + f);
        g8[k] = gid[r0 + k];                 // wave-uniform
    }

    float gsx = 0.f, gsy = 0.f, gqx = 0.f, gqy = 0.f;
    int cur = g8[0];
    int runStart = 0;
#pragma unroll
    for (int k = 0; k < 8; ++k) {
        if (g8[k] != cur) {
            atomicAdd(&gsum[cur * NF + f],     gsx);
            atomicAdd(&gsum[cur * NF + f + 1], gsy);
            atomicAdd(&gsq [cur * NF + f],     gqx);
            atomicAdd(&gsq [cur * NF + f + 1], gqy);
            if (lane == 0) atomicAdd(&cnt[cur], k - runStart);
            gsx = gsy = gqx = gqy = 0.f;
            cur = g8[k]; runStart = k;
        }
        gsx += v[k].x; gsy += v[k].y;
        gqx += v[k].x * v[k].x; gqy += v[k].y * v[k].y;
    }
    atomicAdd(&gsum[cur * NF + f],     gsx);
    atomicAdd(&gsum[cur * NF + f + 1], gsy);
    atomicAdd(&gsq [cur * NF + f],     gqx);
    atomicAdd(&gsq [cur * NF + f + 1], gqy);
    if (lane == 0) atomicAdd(&cnt[cur], 8 - runStart);
}

// ================= K2: segment alloc (scan-free) ∥ batch reduction =================
__global__ __launch_bounds__(256) void k2_alloc_bred(
    const int* __restrict__ deg, int2* __restrict__ odeg, int* __restrict__ cursor,
    int* __restrict__ total,
    const float* __restrict__ gsum, const float* __restrict__ gsq,
    float* __restrict__ bsum, float* __restrict__ bsq)
{
    if (blockIdx.x < ALLOC_NB) {
        const int i = blockIdx.x * 256 + threadIdx.x;
        const int lane = threadIdx.x & 63;
        int d = (i < N_NODES) ? deg[i] : 0;
        int p = d;                           // inclusive wave prefix sum
#pragma unroll
        for (int st = 1; st < 64; st <<= 1) {
            int v = __shfl_up(p, st, 64);
            if (lane >= st) p += v;
        }
        int wtot = __shfl(p, 63, 64);
        int base = 0;
        if (lane == 63) base = atomicAdd(total, wtot);
        base = __shfl(base, 63, 64);
        if (i < N_NODES) {
            int o = base + p - d;            // exclusive start of my segment
            odeg[i] = make_int2(o, d);
            cursor[i] = o;
        }
    } else {
        // bsum[f] = sum_g gsum[g][f]
        int b = blockIdx.x - ALLOC_NB;
        int t = threadIdx.x;
        int f = t & 127, gl = t >> 7;
        float s = 0.f, q = 0.f;
#pragma unroll
        for (int k = 0; k < 8; ++k) {
            int g = b * 16 + gl * 8 + k;
            if (g < NG) { s += gsum[g * NF + f]; q += gsq[g * NF + f]; }
        }
        atomicAdd(&bsum[f], s);
        atomicAdd(&bsq[f], q);
    }
}

// ================= K3: CSR fill ∥ prep (tables -> mu/rstd, feature constants) =================
// fc[f*8] = { mb, rvb, w0*g/s, w1*g/s, w2*g/s, w3*g/s, beta, 0 }
__global__ __launch_bounds__(256) void k3_fill_prep(
    const int* __restrict__ esrc, const int* __restrict__ edst,
    int* __restrict__ cursor, int* __restrict__ nbr,
    float* __restrict__ gsum, float* __restrict__ gsq, const int* __restrict__ cnt,
    const float* __restrict__ bsum, const float* __restrict__ bsq,
    const float* __restrict__ gamma, const float* __restrict__ beta,
    const float* __restrict__ lb, const float* __restrict__ lg,
    const float* __restrict__ la, const float* __restrict__ ln,
    float* __restrict__ fc)
{
    if (blockIdx.x < DEG_NB) {
        int t = blockIdx.x * 256 + threadIdx.x;
        if (t < NE / 4) {
            const int4 d4 = reinterpret_cast<const int4*>(edst)[t];
            const int4 s4 = reinterpret_cast<const int4*>(esrc)[t];
            int p;
            p = atomicAdd(&cursor[d4.x], 1); nbr[p] = s4.x;
            p = atomicAdd(&cursor[d4.y], 1); nbr[p] = s4.y;
            p = atomicAdd(&cursor[d4.z], 1); nbr[p] = s4.z;
            p = atomicAdd(&cursor[d4.w], 1); nbr[p] = s4.w;
        }
        return;
    }
    int b = blockIdx.x - DEG_NB;
    if (b < (NG * NF) / 256) {               // 500 blocks: elementwise convert
        int idx = b * 256 + threadIdx.x;
        int g = idx >> 7;
        float c = (float)cnt[g]; if (c < 1.f) c = 1.f;
        float rc = 1.0f / c;
        float m = gsum[idx] * rc;
        float v = gsq[idx] * rc - m * m; if (v < 0.f) v = 0.f;
        gsum[idx] = m;
        gsq[idx]  = rsqrtf(v + EPSF);
    } else if (threadIdx.x < NF) {           // last block: per-feature constants
        int f = threadIdx.x;
        float mb = bsum[f] * (1.0f / N_NODES);
        float vb = bsq[f] * (1.0f / N_NODES) - mb * mb;   // no clamp: matches reference
        float rvb = rsqrtf(vb + EPSF);
        float l0 = lb[f], l1 = lg[f], l2 = la[f], l3 = ln[f];
        float m = fmaxf(fmaxf(l0, l1), fmaxf(l2, l3));
        float w0 = __expf(l0 - m), w1 = __expf(l1 - m), w2 = __expf(l2 - m), w3 = __expf(l3 - m);
        float rs = gamma[f] / (w0 + w1 + w2 + w3);
        float* p = fc + f * 8;
        p[0] = mb; p[1] = rvb;
        p[2] = w0 * rs; p[3] = w1 * rs; p[4] = w2 * rs; p[5] = w3 * rs;
        p[6] = beta[f]; p[7] = 0.f;
    }
}

// ================= K5: fused final — tables, gather-first, uniform tail =================
__global__ __launch_bounds__(256) void k5_final(
    const float* __restrict__ x, const int* __restrict__ gid,
    const float* __restrict__ gmu, const float* __restrict__ grs,
    const float* __restrict__ fc, const int2* __restrict__ odeg,
    const int* __restrict__ nbr, float* __restrict__ out)
{
    const int wave = threadIdx.x >> 6;
    const int lane = threadIdx.x & 63;
    const int i = blockIdx.x * 4 + wave;
    const int f = lane * 2;

    // ---- adjacency gather first (longest latency) ----
    const int2 od = odeg[i];
    const int s0 = od.x, dg = od.y;
    float asx = 0.f, asy = 0.f, aqx = 0.f, aqy = 0.f;
    int e = 0;
    for (; e + 8 <= dg; e += 8) {            // full batches: no predication math
        int idx[8];
#pragma unroll
        for (int k = 0; k < 8; ++k) idx[k] = nbr[s0 + e + k];
#pragma unroll
        for (int k = 0; k < 8; ++k) {
            const float2 v = *reinterpret_cast<const float2*>(x + (size_t)idx[k] * NF + f);
            asx += v.x; asy += v.y;
            aqx += v.x * v.x; aqy += v.y * v.y;
        }
    }
    if (e < dg) {                            // wave-uniform tail: predicated batch
        int idx[8];
#pragma unroll
        for (int k = 0; k < 8; ++k)
            idx[k] = nbr[(e + k < dg) ? (s0 + e + k) : s0];
#pragma unroll
        for (int k = 0; k < 8; ++k) {
            const float2 v = *reinterpret_cast<const float2*>(x + (size_t)idx[k] * NF + f);
            const float m = (e + k < dg) ? 1.f : 0.f;
            asx += m * v.x; asy += m * v.y;
            aqx += m * v.x * v.x; aqy += m * v.y * v.y;
        }
    }

    const float2 xi = *reinterpret_cast<const float2*>(x + (size_t)i * NF + f);

    // per-feature constants: {mb, rvb, w0, w1} {w2, w3, beta, pad}
    const float4 c0 = *reinterpret_cast<const float4*>(fc + f * 8);
    const float4 c1 = *reinterpret_cast<const float4*>(fc + f * 8 + 4);
    const float4 d0 = *reinterpret_cast<const float4*>(fc + (f + 1) * 8);
    const float4 d1 = *reinterpret_cast<const float4*>(fc + (f + 1) * 8 + 4);

    // ---- batch norm ----
    float xbx = (xi.x - c0.x) * c0.y;
    float xby = (xi.y - d0.x) * d0.y;

    // ---- graph norm ----
    const int g = gid[i];
    const float2 mg = *reinterpret_cast<const float2*>(gmu + (size_t)g * NF + f);
    const float2 rg = *reinterpret_cast<const float2*>(grs + (size_t)g * NF + f);
    float xgx = (xi.x - mg.x) * rg.x;
    float xgy = (xi.y - mg.y) * rg.y;

    // ---- node norm (wave reductions) ----
    float s = xi.x + xi.y;
#pragma unroll
    for (int d = 1; d < 64; d <<= 1) s += __shfl_xor(s, d, 64);
    const float mn = s * (1.0f / NF);
    float dxx = xi.x - mn, dyy = xi.y - mn;
    float q = dxx * dxx + dyy * dyy;
#pragma unroll
    for (int d = 1; d < 64; d <<= 1) q += __shfl_xor(q, d, 64);
    const float rvn = rsqrtf(q * (1.0f / NF) + EPSF);
    float xnx = dxx * rvn, xny = dyy * rvn;

    // ---- adjacency finish ----
    float dgc = (float)dg; if (dgc < 1.f) dgc = 1.f;
    float rdg = 1.0f / dgc;
    float max_ = asx * rdg, may_ = asy * rdg;
    float vax = aqx * rdg - max_ * max_; if (vax < 0.f) vax = 0.f;
    float vay = aqy * rdg - may_ * may_; if (vay < 0.f) vay = 0.f;
    float xax = (xi.x - max_) * rsqrtf(vax + EPSF);
    float xay = (xi.y - may_) * rsqrtf(vay + EPSF);

    // ---- combine (softmax(lambda)*gamma pre-folded) ----
    float outx = c0.z * xbx + c0.w * xgx + c1.x * xax + c1.y * xnx + c1.z;
    float outy = d0.z * xby + d0.w * xgy + d1.x * xay + d1.y * xny + d1.z;
    *reinterpret_cast<float2*>(out + (size_t)i * NF + f) = make_float2(outx, outy);
}

extern "C" void kernel_launch(void* const* d_in, const int* in_sizes, int n_in,
                              void* d_out, int out_size, void* d_ws, size_t ws_size,
                              hipStream_t stream) {
    const float* x     = (const float*)d_in[0];
    const float* gamma = (const float*)d_in[1];
    const float* beta  = (const float*)d_in[2];
    const float* lb    = (const float*)d_in[3];
    const float* lg    = (const float*)d_in[4];
    const float* la    = (const float*)d_in[5];
    const float* ln    = (const float*)d_in[6];
    const int*   gid   = (const int*)d_in[7];
    const int*   esrc  = (const int*)d_in[8];
    const int*   edst  = (const int*)d_in[9];
    float*       out   = (float*)d_out;

    // ---- workspace layout (4B units); zeroed region first ----
    float* ws    = (float*)d_ws;
    float* bsum  = ws;                              // 128
    float* bsq   = bsum + NF;                       // 128
    float* gsum  = bsq + NF;                        // NG*NF (becomes gmu)
    float* gsq   = gsum + (size_t)NG * NF;          // NG*NF (becomes grs)
    int*   cnt   = (int*)(gsq + (size_t)NG * NF);   // NG
    int*   deg   = cnt + NG;                        // N
    int*   total = deg + N_NODES;                   // 1 (+1 pad)
    // ---- zeroed region ends here ----
    int*   cursor= total + 2;                       // N
    int2*  odeg  = (int2*)(cursor + N_NODES);       // N int2 (8B-aligned)
    int*   nbr   = (int*)(odeg + N_NODES);          // NE
    float* fc    = (float*)(nbr + NE);              // NF*8

    const size_t zero_elems = (size_t)2 * NF + (size_t)2 * NG * NF + NG + N_NODES + 2;
    hipMemsetAsync(d_ws, 0, zero_elems * sizeof(float), stream);

    k1_stats_deg<<<STATS_NB + DEG_NB, 256, 0, stream>>>(
        x, gid, edst, gsum, gsq, cnt, deg);
    k2_alloc_bred<<<ALLOC_NB + BRED_NB, 256, 0, stream>>>(
        deg, odeg, cursor, total, gsum, gsq, bsum, bsq);
    k3_fill_prep<<<DEG_NB + PREP_NB, 256, 0, stream>>>(
        esrc, edst, cursor, nbr, gsum, gsq, cnt, bsum, bsq,
        gamma, beta, lb, lg, la, ln, fc);
    k5_final<<<N_NODES / 4, 256, 0, stream>>>(
        x, gid, gsum, gsq, fc, odeg, nbr, out);
}